// Round 5
// baseline (718.051 us; speedup 1.0000x reference)
//
#include <hip/hip_runtime.h>
#include <cstdint>
#include <cstddef>

#define B_   8
#define N_   8192
#define S_   2048
#define D1_  256
#define D2_  256
#define CIN_ 512

typedef __bf16 bf16x8 __attribute__((ext_vector_type(8)));
typedef float  f32x4  __attribute__((ext_vector_type(4)));
typedef unsigned short u16x4 __attribute__((ext_vector_type(4)));

__device__ __forceinline__ unsigned short f2bf(float f) {
  unsigned u = __builtin_bit_cast(unsigned, f);
  u += 0x7fffu + ((u >> 16) & 1u);
  return (unsigned short)(u >> 16);
}
__device__ __forceinline__ float bf2f(unsigned short h) {
  unsigned u = ((unsigned)h) << 16;
  return __builtin_bit_cast(float, u);
}

__device__ __forceinline__ void gload16(const void* g, void* l) {
  __builtin_amdgcn_global_load_lds(
      (__attribute__((address_space(1))) void*)const_cast<void*>(g),
      (__attribute__((address_space(3))) void*)l, 16, 0, 0);
}

// ================= phase 1 mega-kernel =================
// blocks [0,1024)    : 3-NN search, S scanned in 2 halves (16.4 KB LDS)
// blocks [1024,5120) : transpose points1 -> X0 cols 0..255 (bf16)
// blocks [5120,6144) : transpose points2 -> p2t f32
// blocks [6144,6784) : weight casts f32->bf16
// block  6784        : zero sums+counters (replaces hipMemsetAsync)
// LDS per block ~16.6 KB (was 33 KB): 4 NN + ~4 memory blocks now co-reside
// per CU, so transpose/cast traffic hides under NN's VALU shadow.

#define NB_NN   1024
#define NB_TP1  4096
#define NB_TP2  1024
#define NB_CAST 640
#define NB_TOT  (NB_NN + NB_TP1 + NB_TP2 + NB_CAST + 1)

__device__ __forceinline__ void ins_lex(float d, int i,
                                        float& d0, int& i0,
                                        float& d1, int& i1,
                                        float& d2, int& i2) {
  bool c2 = (d < d2) || (d == d2 && i < i2);
  if (c2) {
    bool c1 = (d < d1) || (d == d1 && i < i1);
    if (c1) {
      d2 = d1; i2 = i1;
      bool c0 = (d < d0) || (d == d0 && i < i0);
      if (c0) { d1 = d0; i1 = i0; d0 = d; i0 = i; }
      else    { d1 = d;  i1 = i; }
    } else    { d2 = d;  i2 = i; }
  }
}

__global__ __launch_bounds__(256, 8) void phase1_kernel(
    const float* __restrict__ xyz1, const float* __restrict__ xyz2,
    const float* __restrict__ points1, const float* __restrict__ points2,
    const float* __restrict__ w0, const float* __restrict__ w1,
    const float* __restrict__ w2,
    int4* __restrict__ idx_out, float4* __restrict__ w_out,
    unsigned short* __restrict__ X0, float* __restrict__ p2t,
    unsigned short* __restrict__ wb0, unsigned short* __restrict__ wb1,
    unsigned short* __restrict__ wb2, float* __restrict__ zero_region) {
  __shared__ __align__(16) char smem[16640];  // max(NN 16384, tile 64x65 f32)
  const int bid = blockIdx.x;
  const int t = threadIdx.x;

  if (bid < NB_NN) {
    // ---- 3-NN: 4 lanes/point, 2 S-halves, bit-identical distance assoc ----
#pragma clang fp contract(off)
    f32x4* q = (f32x4*)smem;  // [1024] x,y,z,|q|^2
    int b = bid >> 7;
    int bx = bid & 127;
    const float* x2 = xyz2 + (size_t)b * 3 * S_;
    const int j = t & 3;
    const int j2 = j << 1;
    const int pt = bx * 64 + (t >> 2);
    const float* x1 = xyz1 + (size_t)b * 3 * N_;
    float px = x1[pt], py = x1[N_ + pt], pz = x1[2 * N_ + pt];
    float n1 = (px * px + py * py) + pz * pz;

    float d0 = 3.4e38f, d1 = 3.4e38f, d2 = 3.4e38f;
    int i0 = -1, i1 = -1, i2 = -1;
    const int sbase = j * 256;

    for (int half = 0; half < 2; half++) {
      const int hb = half * 1024;
      __syncthreads();  // previous scan done before overwriting q
      for (int i = t; i < 1024; i += 256) {
        float a = x2[hb + i], c = x2[S_ + hb + i], d = x2[2 * S_ + hb + i];
        q[i] = f32x4{a, c, d, (a * a + c * c) + d * d};
      }
      __syncthreads();
      // lane-group j starts at candidate 2j: word offset 1032j -> banks
      // {0,8,16,24}, conflict-free b128 broadcasts across the wave.
      for (int s = 0; s < 256; s += 2) {
        int idx = (s + j2) & 255;          // even, so idx+1 never wraps
        f32x4 qa = q[sbase + idx];
        f32x4 qb = q[sbase + idx + 1];
        float dota = (px * qa.x + py * qa.y) + pz * qa.z;
        float da = (-2.0f * dota + n1) + qa.w;
        float dotb = (px * qb.x + py * qb.y) + pz * qb.z;
        float db = (-2.0f * dotb + n1) + qb.w;
        if (da < d2) {
          int ia = hb + sbase + idx;
          if (da < d1) {
            d2 = d1; i2 = i1;
            if (da < d0) { d1 = d0; i1 = i0; d0 = da; i0 = ia; }
            else         { d1 = da; i1 = ia; }
          } else         { d2 = da; i2 = ia; }
        }
        if (db < d2) {
          int ib_ = hb + sbase + idx + 1;
          if (db < d1) {
            d2 = d1; i2 = i1;
            if (db < d0) { d1 = d0; i1 = i0; d0 = db; i0 = ib_; }
            else         { d1 = db; i1 = ib_; }
          } else         { d2 = db; i2 = ib_; }
        }
      }
    }

#pragma unroll
    for (int m = 1; m <= 2; m <<= 1) {
      float e0 = __shfl_xor(d0, m), e1 = __shfl_xor(d1, m), e2 = __shfl_xor(d2, m);
      int f0 = __shfl_xor(i0, m), f1 = __shfl_xor(i1, m), f2 = __shfl_xor(i2, m);
      ins_lex(e0, f0, d0, i0, d1, i1, d2, i2);
      ins_lex(e1, f1, d0, i0, d1, i1, d2, i2);
      ins_lex(e2, f2, d0, i0, d1, i1, d2, i2);
    }

    if (j == 0) {
      float r0 = 1.0f / (d0 + 1e-8f), r1 = 1.0f / (d1 + 1e-8f), r2 = 1.0f / (d2 + 1e-8f);
      float rs = r0 + r1 + r2;
      int p = b * N_ + pt;
      idx_out[p] = make_int4(i0, i1, i2, 0);
      w_out[p] = make_float4(r0 / rs, r1 / rs, r2 / rs, 0.f);
    }
  } else if (bid < NB_NN + NB_TP1) {
    // ---- points1 [B][256][8192] f32 -> X0 [B][8192][512] bf16 (cols 0..255)
    float (*tile)[65] = (float(*)[65])smem;
    int local = bid - NB_NN;
    int b = local >> 9;
    int rem = local & 511;
    int c0 = (rem >> 7) * 64;
    int n0 = (rem & 127) * 64;
    const float* ib = points1 + ((size_t)b * D1_ + c0) * N_ + n0;
    int tx = t & 63, ty4 = t >> 6;
#pragma unroll
    for (int jj = 0; jj < 16; jj++) {
      int row = ty4 + jj * 4;
      tile[row][tx] = ib[(size_t)row * N_ + tx];
    }
    __syncthreads();
    unsigned short* ob = X0 + (size_t)b * N_ * CIN_;
    int tx2 = (t & 31) * 2, ty8 = t >> 5;
#pragma unroll
    for (int jj = 0; jj < 8; jj++) {
      int row = ty8 + jj * 8;  // n offset
      unsigned v = (unsigned)f2bf(tile[tx2][row]) |
                   ((unsigned)f2bf(tile[tx2 + 1][row]) << 16);
      *(unsigned*)(ob + (size_t)(n0 + row) * CIN_ + c0 + tx2) = v;
    }
  } else if (bid < NB_NN + NB_TP1 + NB_TP2) {
    // ---- points2 [B][256][2048] f32 -> p2t [B][2048][256] f32
    float (*tile)[65] = (float(*)[65])smem;
    int local = bid - (NB_NN + NB_TP1);
    int b = local >> 7;
    int rem = local & 127;
    int c0 = (rem >> 5) * 64;
    int s0 = (rem & 31) * 64;
    const float* ib = points2 + ((size_t)b * D2_ + c0) * S_ + s0;
    int tx = t & 63, ty4 = t >> 6;
#pragma unroll
    for (int jj = 0; jj < 16; jj++) {
      int row = ty4 + jj * 4;
      tile[row][tx] = ib[(size_t)row * S_ + tx];
    }
    __syncthreads();
    float* ob = p2t + (size_t)b * S_ * D2_;
#pragma unroll
    for (int jj = 0; jj < 16; jj++) {
      int row = ty4 + jj * 4;  // s offset
      ob[(size_t)(s0 + row) * D2_ + c0 + tx] = tile[tx][row];
    }
  } else if (bid < NB_NN + NB_TP1 + NB_TP2 + NB_CAST) {
    // ---- weight casts
    int local = bid - (NB_NN + NB_TP1 + NB_TP2);
    const float* src;
    unsigned short* dst;
    int off;
    if (local < 256)      { src = w0; dst = wb0; off = local * 1024; }
    else if (local < 512) { src = w1; dst = wb1; off = (local - 256) * 1024; }
    else                  { src = w2; dst = wb2; off = (local - 512) * 1024; }
    int base = off + t * 4;
    float4 v = *(const float4*)(src + base);
    u16x4 o;
    o.x = f2bf(v.x); o.y = f2bf(v.y); o.z = f2bf(v.z); o.w = f2bf(v.w);
    *(u16x4*)(dst + base) = o;
  } else {
    // ---- zero sums (12288 B) + counters (256 B) = 3136 words
    for (int k = t; k < 3136; k += 256) zero_region[k] = 0.f;
  }
}

// ================= weighted interp -> X0 cols 256..511 =================
// XCD swizzle: blockIdx%8 == batch, so each XCD's gathers stay inside its
// own L2-resident 2.1 MB p2t slice.

__global__ __launch_bounds__(256) void interp_kernel(
    const float* __restrict__ p2t, const int4* __restrict__ idx_in,
    const float4* __restrict__ w_in, unsigned short* __restrict__ X0) {
  int wave = threadIdx.x >> 6, lane = threadIdx.x & 63;
  int i = blockIdx.x;
  int g = ((i & 7) << 11) | (i >> 3);
  int p = g * 4 + wave;
  int b = p >> 13;
  int4 id = idx_in[p];
  float4 wt = w_in[p];
  const f32x4* r0 = (const f32x4*)(p2t + ((size_t)b * S_ + id.x) * D2_);
  const f32x4* r1 = (const f32x4*)(p2t + ((size_t)b * S_ + id.y) * D2_);
  const f32x4* r2 = (const f32x4*)(p2t + ((size_t)b * S_ + id.z) * D2_);
  f32x4 a0 = r0[lane], a1 = r1[lane], a2 = r2[lane];
  f32x4 v = wt.x * a0 + wt.y * a1 + wt.z * a2;
  u16x4 o;
  o.x = f2bf(v.x); o.y = f2bf(v.y); o.z = f2bf(v.z); o.w = f2bf(v.w);
  *(u16x4*)(X0 + (size_t)p * CIN_ + D2_ + lane * 4) = o;
}

// ================= bf16 MFMA GEMM (m97 structure, XOR-swizzled LDS) ========
// Unchanged from round 4 (known-good).

template <int O, int EPI>
__global__ __launch_bounds__(256) void gemm_kernel(
    const unsigned short* __restrict__ Wb, const unsigned short* __restrict__ X,
    void* __restrict__ Yout) {
  __shared__ unsigned short As[128 * 32];
  __shared__ unsigned short Bs[128 * 32];
  const int tid = threadIdx.x;
  const int wave = tid >> 6, lane = tid & 63;
  const int wm = wave >> 1, wn = wave & 1;
  const int quad = lane >> 4, l16 = lane & 15;
  const int M0 = blockIdx.y * 128;
  const int N0 = blockIdx.x * 128;
  const unsigned short* Xb = X + (size_t)blockIdx.z * N_ * CIN_;

  const int arow = tid >> 2;
  const int qsw = ((tid & 3) - (tid >> 4)) & 3;
  const char* Ag = (const char*)Wb + (size_t)(M0 + arow) * (CIN_ * 2) + qsw * 16;
  const char* Bg = (const char*)Xb + (size_t)(N0 + arow) * (CIN_ * 2) + qsw * 16;
  char* AsW0 = (char*)As + wave * 1024;
  char* AsW1 = (char*)As + 4096 + wave * 1024;
  char* BsW0 = (char*)Bs + wave * 1024;
  char* BsW1 = (char*)Bs + 4096 + wave * 1024;
  const int rstep = 64 * (CIN_ * 2);
  const int csw = (quad + (l16 >> 2)) & 3;

  f32x4 acc[4][4];
#pragma unroll
  for (int i = 0; i < 4; i++)
#pragma unroll
    for (int j = 0; j < 4; j++) acc[i][j] = f32x4{0.f, 0.f, 0.f, 0.f};

  for (int k0 = 0; k0 < CIN_; k0 += 32) {
    gload16(Ag + (size_t)k0 * 2, AsW0);
    gload16(Ag + rstep + (size_t)k0 * 2, AsW1);
    gload16(Bg + (size_t)k0 * 2, BsW0);
    gload16(Bg + rstep + (size_t)k0 * 2, BsW1);
    __syncthreads();
    bf16x8 af[4], bfr[4];
#pragma unroll
    for (int mt = 0; mt < 4; mt++)
      af[mt] = *(const bf16x8*)(As + (wm * 64 + mt * 16 + l16) * 32 + csw * 8);
#pragma unroll
    for (int nt = 0; nt < 4; nt++)
      bfr[nt] = *(const bf16x8*)(Bs + (wn * 64 + nt * 16 + l16) * 32 + csw * 8);
#pragma unroll
    for (int mt = 0; mt < 4; mt++)
#pragma unroll
      for (int nt = 0; nt < 4; nt++)
        acc[mt][nt] = __builtin_amdgcn_mfma_f32_16x16x32_bf16(af[mt], bfr[nt], acc[mt][nt], 0, 0, 0);
    __syncthreads();
  }

  if constexpr (EPI == 0) {
    unsigned short* Y = (unsigned short*)Yout + (size_t)blockIdx.z * N_ * O;
#pragma unroll
    for (int mt = 0; mt < 4; mt++) {
#pragma unroll
      for (int nt = 0; nt < 4; nt++) {
        int o = M0 + wm * 64 + mt * 16 + quad * 4;
        int n = N0 + wn * 64 + nt * 16 + l16;
        u16x4 v;
        v.x = f2bf(acc[mt][nt].x);
        v.y = f2bf(acc[mt][nt].y);
        v.z = f2bf(acc[mt][nt].z);
        v.w = f2bf(acc[mt][nt].w);
        *(u16x4*)(Y + (size_t)n * O + o) = v;
      }
    }
  } else {
    float* Y = (float*)Yout + (size_t)blockIdx.z * (size_t)O * N_;
#pragma unroll
    for (int mt = 0; mt < 4; mt++) {
#pragma unroll
      for (int nt = 0; nt < 4; nt++) {
        int o = M0 + wm * 64 + mt * 16 + quad * 4;
        int n = N0 + wn * 64 + nt * 16 + l16;
#pragma unroll
        for (int r = 0; r < 4; r++)
          Y[(size_t)(o + r) * N_ + n] = acc[mt][nt][r];
      }
    }
  }
}

// ================= BN stats + last-block finalize =================

// Y bf16 [65536 rows][512]; grid 512 blocks x 128 rows. Last block computes
// sc/sh into ss (counter zeroed by phase1 every call).
__global__ __launch_bounds__(256) void stats_bf16_kernel(
    const unsigned short* __restrict__ Y, float* __restrict__ sums,
    int* __restrict__ counter, const float* __restrict__ g,
    const float* __restrict__ beta, float* __restrict__ ss) {
  int t = threadIdx.x;
  int c = t * 2;
  size_t row0 = (size_t)blockIdx.x * 128;
  float s0 = 0, s1 = 0, q0 = 0, q1 = 0;
#pragma unroll 4
  for (int r = 0; r < 128; r++) {
    unsigned v = *(const unsigned*)(Y + (row0 + r) * CIN_ + c);
    float f0 = bf2f((unsigned short)(v & 0xffff));
    float f1 = bf2f((unsigned short)(v >> 16));
    s0 += f0; s1 += f1; q0 += f0 * f0; q1 += f1 * f1;
  }
  atomicAdd(&sums[c], s0);
  atomicAdd(&sums[c + 1], s1);
  atomicAdd(&sums[512 + c], q0);
  atomicAdd(&sums[512 + c + 1], q1);
  __threadfence();
  __syncthreads();
  __shared__ int last;
  if (t == 0) last = (atomicAdd(counter, 1) == (int)gridDim.x - 1);
  __syncthreads();
  if (last) {
    const float inv = 1.0f / 65536.0f;
    for (int cc = t; cc < 512; cc += 256) {
      float sm = atomicAdd(&sums[cc], 0.f);
      float sq = atomicAdd(&sums[512 + cc], 0.f);
      float mean = sm * inv;
      float var = sq * inv - mean * mean;
      float rstd = 1.0f / sqrtf(var + 1e-5f);
      float sc = g[cc] * rstd;
      ss[cc] = sc;
      ss[512 + cc] = beta[cc] - mean * sc;
    }
  }
}

// Y2 f32 [8][256][8192]; grid (256,8). Last block finalizes 256 channels.
__global__ __launch_bounds__(256) void stats_f32_kernel(
    const float* __restrict__ Y2, float* __restrict__ sums,
    int* __restrict__ counter, const float* __restrict__ g,
    const float* __restrict__ beta, float* __restrict__ ss) {
  int o = blockIdx.x, b = blockIdx.y, t = threadIdx.x;
  const float* row = Y2 + ((size_t)b * 256 + o) * N_;
  float s = 0, q = 0;
#pragma unroll
  for (int j = 0; j < 8; j++) {
    f32x4 v = *(const f32x4*)(row + (size_t)(t + j * 256) * 4);
    s += (v.x + v.y) + (v.z + v.w);
    q += (v.x * v.x + v.y * v.y) + (v.z * v.z + v.w * v.w);
  }
  __shared__ float rs[256], rq[256];
  rs[t] = s; rq[t] = q;
  __syncthreads();
  for (int off = 128; off > 0; off >>= 1) {
    if (t < off) { rs[t] += rs[t + off]; rq[t] += rq[t + off]; }
    __syncthreads();
  }
  if (t == 0) {
    atomicAdd(&sums[o], rs[0]);
    atomicAdd(&sums[512 + o], rq[0]);
  }
  __threadfence();
  __syncthreads();
  __shared__ int last;
  if (t == 0) last = (atomicAdd(counter, 1) == (int)(gridDim.x * gridDim.y) - 1);
  __syncthreads();
  if (last && t < 256) {
    const float inv = 1.0f / 65536.0f;
    float sm = atomicAdd(&sums[t], 0.f);
    float sq = atomicAdd(&sums[512 + t], 0.f);
    float mean = sm * inv;
    float var = sq * inv - mean * mean;
    float rstd = 1.0f / sqrtf(var + 1e-5f);
    float sc = g[t] * rstd;
    ss[t] = sc;
    ss[512 + t] = beta[t] - mean * sc;
  }
}

// ================= normalize + relu (read precomputed sc/sh) ============

__global__ __launch_bounds__(256) void norm_bf16_kernel(
    unsigned short* __restrict__ Y, const float* __restrict__ ss) {
  __shared__ float sc[512], sh[512];
  int t = threadIdx.x;
  sc[t] = ss[t]; sc[t + 256] = ss[t + 256];
  sh[t] = ss[512 + t]; sh[t + 256] = ss[768 + t];
  __syncthreads();
  size_t base = ((size_t)blockIdx.x * 256 + t) * 8;
  int o = (int)(base & 511);
  uint4 raw = *(const uint4*)(Y + base);
  unsigned vv[4] = {raw.x, raw.y, raw.z, raw.w};
#pragma unroll
  for (int j = 0; j < 4; j++) {
    int c = o + j * 2;
    float f0 = bf2f((unsigned short)(vv[j] & 0xffff));
    float f1 = bf2f((unsigned short)(vv[j] >> 16));
    f0 = fmaxf(f0 * sc[c] + sh[c], 0.f);
    f1 = fmaxf(f1 * sc[c + 1] + sh[c + 1], 0.f);
    vv[j] = (unsigned)f2bf(f0) | ((unsigned)f2bf(f1) << 16);
  }
  raw.x = vv[0]; raw.y = vv[1]; raw.z = vv[2]; raw.w = vv[3];
  *(uint4*)(Y + base) = raw;
}

__global__ __launch_bounds__(256) void norm_out_kernel(
    float* __restrict__ Y2, const float* __restrict__ ss) {
  int o = blockIdx.y;
  float sc = ss[o], sh = ss[512 + o];
  size_t base = ((size_t)blockIdx.z * 256 + o) * N_ + (size_t)blockIdx.x * 1024 +
                (size_t)threadIdx.x * 4;
  f32x4 v = *(const f32x4*)(Y2 + base);
  v = v * sc + sh;
  v.x = fmaxf(v.x, 0.f); v.y = fmaxf(v.y, 0.f);
  v.z = fmaxf(v.z, 0.f); v.w = fmaxf(v.w, 0.f);
  *(f32x4*)(Y2 + base) = v;
}

// ================= launch =================

extern "C" void kernel_launch(void* const* d_in, const int* in_sizes, int n_in,
                              void* d_out, int out_size, void* d_ws, size_t ws_size,
                              hipStream_t stream) {
  const float* xyz1 = (const float*)d_in[0];
  const float* xyz2 = (const float*)d_in[1];
  const float* points1 = (const float*)d_in[2];
  const float* points2 = (const float*)d_in[3];
  const float* w0 = (const float*)d_in[4];
  const float* g0 = (const float*)d_in[6];
  const float* be0 = (const float*)d_in[7];
  const float* w1 = (const float*)d_in[8];
  const float* g1 = (const float*)d_in[10];
  const float* be1 = (const float*)d_in[11];
  const float* w2 = (const float*)d_in[12];
  const float* g2 = (const float*)d_in[14];
  const float* be2 = (const float*)d_in[15];

  char* ws = (char*)d_ws;
  unsigned short* bufA = (unsigned short*)ws;                     // 67,108,864 B
  unsigned short* bufB = (unsigned short*)(ws + 67108864);        // 67,108,864 B
  float* p2t          = (float*)(ws + 134217728);                 // 16,777,216 B
  unsigned short* wb0 = (unsigned short*)(ws + 150994944);        // 524,288 B
  unsigned short* wb1 = (unsigned short*)(ws + 151519232);        // 524,288 B
  unsigned short* wb2 = (unsigned short*)(ws + 152043520);        // 262,144 B
  int4* idxb          = (int4*)(ws + 152305664);                  // 1,048,576 B
  float4* wtb         = (float4*)(ws + 153354240);                // 1,048,576 B
  float* sums         = (float*)(ws + 154402816);                 // 12,288 B (3 x 1024 f32)
  int* counters       = (int*)(ws + 154402816 + 12288);           // 256 B (3 ints used)
  float* ssb          = (float*)(ws + 154402816 + 12544);         // 12,288 B (3 x 1024 f32)

  phase1_kernel<<<NB_TOT, 256, 0, stream>>>(
      xyz1, xyz2, points1, points2, w0, w1, w2,
      idxb, wtb, bufA, p2t, wb0, wb1, wb2, sums /* zero_region: sums+counters */);

  interp_kernel<<<16384, 256, 0, stream>>>(p2t, idxb, wtb, bufA);

  // layer 0
  gemm_kernel<512, 0><<<dim3(64, 4, 8), 256, 0, stream>>>(wb0, bufA, bufB);
  stats_bf16_kernel<<<512, 256, 0, stream>>>(bufB, sums, counters, g0, be0, ssb);
  norm_bf16_kernel<<<16384, 256, 0, stream>>>(bufB, ssb);

  // layer 1
  gemm_kernel<512, 0><<<dim3(64, 4, 8), 256, 0, stream>>>(wb1, bufB, bufA);
  stats_bf16_kernel<<<512, 256, 0, stream>>>(bufA, sums + 1024, counters + 16, g1, be1, ssb + 1024);
  norm_bf16_kernel<<<16384, 256, 0, stream>>>(bufA, ssb + 1024);

  // layer 2 (f32 epilogue straight into d_out, [b][o][n])
  gemm_kernel<256, 1><<<dim3(64, 2, 8), 256, 0, stream>>>(wb2, bufA, (void*)d_out);
  stats_f32_kernel<<<dim3(256, 8), 256, 0, stream>>>((const float*)d_out, sums + 2048, counters + 32, g2, be2, ssb + 2048);
  norm_out_kernel<<<dim3(8, 256, 8), 256, 0, stream>>>((float*)d_out, ssb + 2048);
}

// Round 6
// 489.299 us; speedup vs baseline: 1.4675x; 1.4675x over previous
//
#include <hip/hip_runtime.h>
#include <cstdint>
#include <cstddef>

#define B_   8
#define N_   8192
#define S_   2048
#define D1_  256
#define D2_  256
#define CIN_ 512

typedef __bf16 bf16x8 __attribute__((ext_vector_type(8)));
typedef float  f32x4  __attribute__((ext_vector_type(4)));
typedef unsigned short u16x4 __attribute__((ext_vector_type(4)));

__device__ __forceinline__ unsigned short f2bf(float f) {
  unsigned u = __builtin_bit_cast(unsigned, f);
  u += 0x7fffu + ((u >> 16) & 1u);
  return (unsigned short)(u >> 16);
}
__device__ __forceinline__ float bf2f(unsigned short h) {
  unsigned u = ((unsigned)h) << 16;
  return __builtin_bit_cast(float, u);
}

__device__ __forceinline__ void gload16(const void* g, void* l) {
  __builtin_amdgcn_global_load_lds(
      (__attribute__((address_space(1))) void*)const_cast<void*>(g),
      (__attribute__((address_space(3))) void*)l, 16, 0, 0);
}

// ================= phase 1 mega-kernel =================
// blocks [0,1024)    : 3-NN search, S scanned in 2 halves (16.4 KB LDS)
// blocks [1024,5120) : transpose points1 -> X0 cols 0..255 (bf16)
// blocks [5120,6144) : transpose points2 -> p2t f32
// blocks [6144,6784) : weight casts f32->bf16
// block  6784        : zero sums (replaces hipMemsetAsync)
// LDS ~16.6 KB/block so NN + memory blocks co-reside per CU (overlap).
// NOTE (r5 lesson): NO __threadfence() anywhere hot — agent-scope fence =
// per-wave L2 writeback/invalidate across XCDs, ~200 us on a 2048-block grid.

#define NB_NN   1024
#define NB_TP1  4096
#define NB_TP2  1024
#define NB_CAST 640
#define NB_TOT  (NB_NN + NB_TP1 + NB_TP2 + NB_CAST + 1)

__device__ __forceinline__ void ins_lex(float d, int i,
                                        float& d0, int& i0,
                                        float& d1, int& i1,
                                        float& d2, int& i2) {
  bool c2 = (d < d2) || (d == d2 && i < i2);
  if (c2) {
    bool c1 = (d < d1) || (d == d1 && i < i1);
    if (c1) {
      d2 = d1; i2 = i1;
      bool c0 = (d < d0) || (d == d0 && i < i0);
      if (c0) { d1 = d0; i1 = i0; d0 = d; i0 = i; }
      else    { d1 = d;  i1 = i; }
    } else    { d2 = d;  i2 = i; }
  }
}

__global__ __launch_bounds__(256, 8) void phase1_kernel(
    const float* __restrict__ xyz1, const float* __restrict__ xyz2,
    const float* __restrict__ points1, const float* __restrict__ points2,
    const float* __restrict__ w0, const float* __restrict__ w1,
    const float* __restrict__ w2,
    int4* __restrict__ idx_out, float4* __restrict__ w_out,
    unsigned short* __restrict__ X0, float* __restrict__ p2t,
    unsigned short* __restrict__ wb0, unsigned short* __restrict__ wb1,
    unsigned short* __restrict__ wb2, float* __restrict__ zero_region) {
  __shared__ __align__(16) char smem[16640];  // max(NN 16384, tile 64x65 f32)
  const int bid = blockIdx.x;
  const int t = threadIdx.x;

  if (bid < NB_NN) {
    // ---- 3-NN: 4 lanes/point, 2 S-halves, bit-identical distance assoc ----
#pragma clang fp contract(off)
    f32x4* q = (f32x4*)smem;  // [1024] x,y,z,|q|^2
    int b = bid >> 7;
    int bx = bid & 127;
    const float* x2 = xyz2 + (size_t)b * 3 * S_;
    const int j = t & 3;
    const int j2 = j << 1;
    const int pt = bx * 64 + (t >> 2);
    const float* x1 = xyz1 + (size_t)b * 3 * N_;
    float px = x1[pt], py = x1[N_ + pt], pz = x1[2 * N_ + pt];
    float n1 = (px * px + py * py) + pz * pz;

    float d0 = 3.4e38f, d1 = 3.4e38f, d2 = 3.4e38f;
    int i0 = -1, i1 = -1, i2 = -1;
    const int sbase = j * 256;

    for (int half = 0; half < 2; half++) {
      const int hb = half * 1024;
      __syncthreads();  // previous scan done before overwriting q
      for (int i = t; i < 1024; i += 256) {
        float a = x2[hb + i], c = x2[S_ + hb + i], d = x2[2 * S_ + hb + i];
        q[i] = f32x4{a, c, d, (a * a + c * c) + d * d};
      }
      __syncthreads();
      for (int s = 0; s < 256; s += 2) {
        int idx = (s + j2) & 255;          // even, so idx+1 never wraps
        f32x4 qa = q[sbase + idx];
        f32x4 qb = q[sbase + idx + 1];
        float dota = (px * qa.x + py * qa.y) + pz * qa.z;
        float da = (-2.0f * dota + n1) + qa.w;
        float dotb = (px * qb.x + py * qb.y) + pz * qb.z;
        float db = (-2.0f * dotb + n1) + qb.w;
        if (da < d2) {
          int ia = hb + sbase + idx;
          if (da < d1) {
            d2 = d1; i2 = i1;
            if (da < d0) { d1 = d0; i1 = i0; d0 = da; i0 = ia; }
            else         { d1 = da; i1 = ia; }
          } else         { d2 = da; i2 = ia; }
        }
        if (db < d2) {
          int ib_ = hb + sbase + idx + 1;
          if (db < d1) {
            d2 = d1; i2 = i1;
            if (db < d0) { d1 = d0; i1 = i0; d0 = db; i0 = ib_; }
            else         { d1 = db; i1 = ib_; }
          } else         { d2 = db; i2 = ib_; }
        }
      }
    }

#pragma unroll
    for (int m = 1; m <= 2; m <<= 1) {
      float e0 = __shfl_xor(d0, m), e1 = __shfl_xor(d1, m), e2 = __shfl_xor(d2, m);
      int f0 = __shfl_xor(i0, m), f1 = __shfl_xor(i1, m), f2 = __shfl_xor(i2, m);
      ins_lex(e0, f0, d0, i0, d1, i1, d2, i2);
      ins_lex(e1, f1, d0, i0, d1, i1, d2, i2);
      ins_lex(e2, f2, d0, i0, d1, i1, d2, i2);
    }

    if (j == 0) {
      float r0 = 1.0f / (d0 + 1e-8f), r1 = 1.0f / (d1 + 1e-8f), r2 = 1.0f / (d2 + 1e-8f);
      float rs = r0 + r1 + r2;
      int p = b * N_ + pt;
      idx_out[p] = make_int4(i0, i1, i2, 0);
      w_out[p] = make_float4(r0 / rs, r1 / rs, r2 / rs, 0.f);
    }
  } else if (bid < NB_NN + NB_TP1) {
    // ---- points1 [B][256][8192] f32 -> X0 [B][8192][512] bf16 (cols 0..255)
    float (*tile)[65] = (float(*)[65])smem;
    int local = bid - NB_NN;
    int b = local >> 9;
    int rem = local & 511;
    int c0 = (rem >> 7) * 64;
    int n0 = (rem & 127) * 64;
    const float* ib = points1 + ((size_t)b * D1_ + c0) * N_ + n0;
    int tx = t & 63, ty4 = t >> 6;
#pragma unroll
    for (int jj = 0; jj < 16; jj++) {
      int row = ty4 + jj * 4;
      tile[row][tx] = ib[(size_t)row * N_ + tx];
    }
    __syncthreads();
    unsigned short* ob = X0 + (size_t)b * N_ * CIN_;
    int tx2 = (t & 31) * 2, ty8 = t >> 5;
#pragma unroll
    for (int jj = 0; jj < 8; jj++) {
      int row = ty8 + jj * 8;  // n offset
      unsigned v = (unsigned)f2bf(tile[tx2][row]) |
                   ((unsigned)f2bf(tile[tx2 + 1][row]) << 16);
      *(unsigned*)(ob + (size_t)(n0 + row) * CIN_ + c0 + tx2) = v;
    }
  } else if (bid < NB_NN + NB_TP1 + NB_TP2) {
    // ---- points2 [B][256][2048] f32 -> p2t [B][2048][256] f32
    float (*tile)[65] = (float(*)[65])smem;
    int local = bid - (NB_NN + NB_TP1);
    int b = local >> 7;
    int rem = local & 127;
    int c0 = (rem >> 5) * 64;
    int s0 = (rem & 31) * 64;
    const float* ib = points2 + ((size_t)b * D2_ + c0) * S_ + s0;
    int tx = t & 63, ty4 = t >> 6;
#pragma unroll
    for (int jj = 0; jj < 16; jj++) {
      int row = ty4 + jj * 4;
      tile[row][tx] = ib[(size_t)row * S_ + tx];
    }
    __syncthreads();
    float* ob = p2t + (size_t)b * S_ * D2_;
#pragma unroll
    for (int jj = 0; jj < 16; jj++) {
      int row = ty4 + jj * 4;  // s offset
      ob[(size_t)(s0 + row) * D2_ + c0 + tx] = tile[tx][row];
    }
  } else if (bid < NB_NN + NB_TP1 + NB_TP2 + NB_CAST) {
    // ---- weight casts
    int local = bid - (NB_NN + NB_TP1 + NB_TP2);
    const float* src;
    unsigned short* dst;
    int off;
    if (local < 256)      { src = w0; dst = wb0; off = local * 1024; }
    else if (local < 512) { src = w1; dst = wb1; off = (local - 256) * 1024; }
    else                  { src = w2; dst = wb2; off = (local - 512) * 1024; }
    int base = off + t * 4;
    float4 v = *(const float4*)(src + base);
    u16x4 o;
    o.x = f2bf(v.x); o.y = f2bf(v.y); o.z = f2bf(v.z); o.w = f2bf(v.w);
    *(u16x4*)(dst + base) = o;
  } else {
    // ---- zero sums: 3072 words (3 layers x 1024 f32)
    for (int k = t; k < 3072; k += 256) zero_region[k] = 0.f;
  }
}

// ================= weighted interp -> X0 cols 256..511 =================
// XCD swizzle: blockIdx%8 == batch, gathers stay in the XCD's L2 p2t slice.

__global__ __launch_bounds__(256) void interp_kernel(
    const float* __restrict__ p2t, const int4* __restrict__ idx_in,
    const float4* __restrict__ w_in, unsigned short* __restrict__ X0) {
  int wave = threadIdx.x >> 6, lane = threadIdx.x & 63;
  int i = blockIdx.x;
  int g = ((i & 7) << 11) | (i >> 3);
  int p = g * 4 + wave;
  int b = p >> 13;
  int4 id = idx_in[p];
  float4 wt = w_in[p];
  const f32x4* r0 = (const f32x4*)(p2t + ((size_t)b * S_ + id.x) * D2_);
  const f32x4* r1 = (const f32x4*)(p2t + ((size_t)b * S_ + id.y) * D2_);
  const f32x4* r2 = (const f32x4*)(p2t + ((size_t)b * S_ + id.z) * D2_);
  f32x4 a0 = r0[lane], a1 = r1[lane], a2 = r2[lane];
  f32x4 v = wt.x * a0 + wt.y * a1 + wt.z * a2;
  u16x4 o;
  o.x = f2bf(v.x); o.y = f2bf(v.y); o.z = f2bf(v.z); o.w = f2bf(v.w);
  *(u16x4*)(X0 + (size_t)p * CIN_ + D2_ + lane * 4) = o;
}

// ================= bf16 MFMA GEMM (m97 structure, XOR-swizzled LDS) ========

template <int O, int EPI>
__global__ __launch_bounds__(256) void gemm_kernel(
    const unsigned short* __restrict__ Wb, const unsigned short* __restrict__ X,
    void* __restrict__ Yout) {
  __shared__ unsigned short As[128 * 32];
  __shared__ unsigned short Bs[128 * 32];
  const int tid = threadIdx.x;
  const int wave = tid >> 6, lane = tid & 63;
  const int wm = wave >> 1, wn = wave & 1;
  const int quad = lane >> 4, l16 = lane & 15;
  const int M0 = blockIdx.y * 128;
  const int N0 = blockIdx.x * 128;
  const unsigned short* Xb = X + (size_t)blockIdx.z * N_ * CIN_;

  const int arow = tid >> 2;
  const int qsw = ((tid & 3) - (tid >> 4)) & 3;
  const char* Ag = (const char*)Wb + (size_t)(M0 + arow) * (CIN_ * 2) + qsw * 16;
  const char* Bg = (const char*)Xb + (size_t)(N0 + arow) * (CIN_ * 2) + qsw * 16;
  char* AsW0 = (char*)As + wave * 1024;
  char* AsW1 = (char*)As + 4096 + wave * 1024;
  char* BsW0 = (char*)Bs + wave * 1024;
  char* BsW1 = (char*)Bs + 4096 + wave * 1024;
  const int rstep = 64 * (CIN_ * 2);
  const int csw = (quad + (l16 >> 2)) & 3;

  f32x4 acc[4][4];
#pragma unroll
  for (int i = 0; i < 4; i++)
#pragma unroll
    for (int j = 0; j < 4; j++) acc[i][j] = f32x4{0.f, 0.f, 0.f, 0.f};

  for (int k0 = 0; k0 < CIN_; k0 += 32) {
    gload16(Ag + (size_t)k0 * 2, AsW0);
    gload16(Ag + rstep + (size_t)k0 * 2, AsW1);
    gload16(Bg + (size_t)k0 * 2, BsW0);
    gload16(Bg + rstep + (size_t)k0 * 2, BsW1);
    __syncthreads();
    bf16x8 af[4], bfr[4];
#pragma unroll
    for (int mt = 0; mt < 4; mt++)
      af[mt] = *(const bf16x8*)(As + (wm * 64 + mt * 16 + l16) * 32 + csw * 8);
#pragma unroll
    for (int nt = 0; nt < 4; nt++)
      bfr[nt] = *(const bf16x8*)(Bs + (wn * 64 + nt * 16 + l16) * 32 + csw * 8);
#pragma unroll
    for (int mt = 0; mt < 4; mt++)
#pragma unroll
      for (int nt = 0; nt < 4; nt++)
        acc[mt][nt] = __builtin_amdgcn_mfma_f32_16x16x32_bf16(af[mt], bfr[nt], acc[mt][nt], 0, 0, 0);
    __syncthreads();
  }

  if constexpr (EPI == 0) {
    unsigned short* Y = (unsigned short*)Yout + (size_t)blockIdx.z * N_ * O;
#pragma unroll
    for (int mt = 0; mt < 4; mt++) {
#pragma unroll
      for (int nt = 0; nt < 4; nt++) {
        int o = M0 + wm * 64 + mt * 16 + quad * 4;
        int n = N0 + wn * 64 + nt * 16 + l16;
        u16x4 v;
        v.x = f2bf(acc[mt][nt].x);
        v.y = f2bf(acc[mt][nt].y);
        v.z = f2bf(acc[mt][nt].z);
        v.w = f2bf(acc[mt][nt].w);
        *(u16x4*)(Y + (size_t)n * O + o) = v;
      }
    }
  } else {
    float* Y = (float*)Yout + (size_t)blockIdx.z * (size_t)O * N_;
#pragma unroll
    for (int mt = 0; mt < 4; mt++) {
#pragma unroll
      for (int nt = 0; nt < 4; nt++) {
        int o = M0 + wm * 64 + mt * 16 + quad * 4;
        int n = N0 + wn * 64 + nt * 16 + l16;
#pragma unroll
        for (int r = 0; r < 4; r++)
          Y[(size_t)(o + r) * N_ + n] = acc[mt][nt][r];
      }
    }
  }
}

// ================= BN stats (plain atomics, NO fences) =================

// Y bf16 [65536 rows][512]; 512 blocks x 128 rows.
__global__ __launch_bounds__(256) void stats_bf16_kernel(
    const unsigned short* __restrict__ Y, float* __restrict__ sums) {
  int t = threadIdx.x;
  int c = t * 2;
  size_t row0 = (size_t)blockIdx.x * 128;
  float s0 = 0, s1 = 0, q0 = 0, q1 = 0;
#pragma unroll 4
  for (int r = 0; r < 128; r++) {
    unsigned v = *(const unsigned*)(Y + (row0 + r) * CIN_ + c);
    float f0 = bf2f((unsigned short)(v & 0xffff));
    float f1 = bf2f((unsigned short)(v >> 16));
    s0 += f0; s1 += f1; q0 += f0 * f0; q1 += f1 * f1;
  }
  atomicAdd(&sums[c], s0);
  atomicAdd(&sums[c + 1], s1);
  atomicAdd(&sums[512 + c], q0);
  atomicAdd(&sums[512 + c + 1], q1);
}

// Y2 f32 [8][256][8192]; grid (256,8): per (o,b) row.
__global__ __launch_bounds__(256) void stats_f32_kernel(
    const float* __restrict__ Y2, float* __restrict__ sums) {
  int o = blockIdx.x, b = blockIdx.y, t = threadIdx.x;
  const float* row = Y2 + ((size_t)b * 256 + o) * N_;
  float s = 0, q = 0;
#pragma unroll
  for (int j = 0; j < 8; j++) {
    f32x4 v = *(const f32x4*)(row + (size_t)(t + j * 256) * 4);
    s += (v.x + v.y) + (v.z + v.w);
    q += (v.x * v.x + v.y * v.y) + (v.z * v.z + v.w * v.w);
  }
  __shared__ float rs[256], rq[256];
  rs[t] = s; rq[t] = q;
  __syncthreads();
  for (int off = 128; off > 0; off >>= 1) {
    if (t < off) { rs[t] += rs[t + off]; rq[t] += rq[t + off]; }
    __syncthreads();
  }
  if (t == 0) {
    atomicAdd(&sums[o], rs[0]);
    atomicAdd(&sums[512 + o], rq[0]);
  }
}

// ================= normalize + relu (inline finalize from sums) ==========

__global__ __launch_bounds__(256) void norm_bf16_kernel(
    unsigned short* __restrict__ Y, const float* __restrict__ sums,
    const float* __restrict__ g, const float* __restrict__ beta) {
  __shared__ float sc[512], sh[512];
  int t = threadIdx.x;
  const float inv = 1.0f / 65536.0f;
#pragma unroll
  for (int cc = 0; cc < 2; cc++) {
    int c = t + cc * 256;
    float mean = sums[c] * inv;
    float var = sums[512 + c] * inv - mean * mean;
    float rstd = 1.0f / sqrtf(var + 1e-5f);
    float s = g[c] * rstd;
    sc[c] = s;
    sh[c] = beta[c] - mean * s;
  }
  __syncthreads();
  size_t base = ((size_t)blockIdx.x * 256 + t) * 8;
  int o = (int)(base & 511);
  uint4 raw = *(const uint4*)(Y + base);
  unsigned vv[4] = {raw.x, raw.y, raw.z, raw.w};
#pragma unroll
  for (int j = 0; j < 4; j++) {
    int c = o + j * 2;
    float f0 = bf2f((unsigned short)(vv[j] & 0xffff));
    float f1 = bf2f((unsigned short)(vv[j] >> 16));
    f0 = fmaxf(f0 * sc[c] + sh[c], 0.f);
    f1 = fmaxf(f1 * sc[c + 1] + sh[c + 1], 0.f);
    vv[j] = (unsigned)f2bf(f0) | ((unsigned)f2bf(f1) << 16);
  }
  raw.x = vv[0]; raw.y = vv[1]; raw.z = vv[2]; raw.w = vv[3];
  *(uint4*)(Y + base) = raw;
}

__global__ __launch_bounds__(256) void norm_out_kernel(
    float* __restrict__ Y2, const float* __restrict__ sums,
    const float* __restrict__ g, const float* __restrict__ beta) {
  int o = blockIdx.y;
  const float inv = 1.0f / 65536.0f;
  float mean = sums[o] * inv;
  float var = sums[512 + o] * inv - mean * mean;
  float rstd = 1.0f / sqrtf(var + 1e-5f);
  float sc = g[o] * rstd;
  float sh = beta[o] - mean * sc;
  size_t base = ((size_t)blockIdx.z * 256 + o) * N_ + (size_t)blockIdx.x * 1024 +
                (size_t)threadIdx.x * 4;
  f32x4 v = *(const f32x4*)(Y2 + base);
  v = v * sc + sh;
  v.x = fmaxf(v.x, 0.f); v.y = fmaxf(v.y, 0.f);
  v.z = fmaxf(v.z, 0.f); v.w = fmaxf(v.w, 0.f);
  *(f32x4*)(Y2 + base) = v;
}

// ================= launch =================

extern "C" void kernel_launch(void* const* d_in, const int* in_sizes, int n_in,
                              void* d_out, int out_size, void* d_ws, size_t ws_size,
                              hipStream_t stream) {
  const float* xyz1 = (const float*)d_in[0];
  const float* xyz2 = (const float*)d_in[1];
  const float* points1 = (const float*)d_in[2];
  const float* points2 = (const float*)d_in[3];
  const float* w0 = (const float*)d_in[4];
  const float* g0 = (const float*)d_in[6];
  const float* be0 = (const float*)d_in[7];
  const float* w1 = (const float*)d_in[8];
  const float* g1 = (const float*)d_in[10];
  const float* be1 = (const float*)d_in[11];
  const float* w2 = (const float*)d_in[12];
  const float* g2 = (const float*)d_in[14];
  const float* be2 = (const float*)d_in[15];

  char* ws = (char*)d_ws;
  unsigned short* bufA = (unsigned short*)ws;                     // 67,108,864 B
  unsigned short* bufB = (unsigned short*)(ws + 67108864);        // 67,108,864 B
  float* p2t          = (float*)(ws + 134217728);                 // 16,777,216 B
  unsigned short* wb0 = (unsigned short*)(ws + 150994944);        // 524,288 B
  unsigned short* wb1 = (unsigned short*)(ws + 151519232);        // 524,288 B
  unsigned short* wb2 = (unsigned short*)(ws + 152043520);        // 262,144 B
  int4* idxb          = (int4*)(ws + 152305664);                  // 1,048,576 B
  float4* wtb         = (float4*)(ws + 153354240);                // 1,048,576 B
  float* sums         = (float*)(ws + 154402816);                 // 12,288 B (3 x 1024 f32)

  phase1_kernel<<<NB_TOT, 256, 0, stream>>>(
      xyz1, xyz2, points1, points2, w0, w1, w2,
      idxb, wtb, bufA, p2t, wb0, wb1, wb2, sums);

  interp_kernel<<<16384, 256, 0, stream>>>(p2t, idxb, wtb, bufA);

  // layer 0
  gemm_kernel<512, 0><<<dim3(64, 4, 8), 256, 0, stream>>>(wb0, bufA, bufB);
  stats_bf16_kernel<<<512, 256, 0, stream>>>(bufB, sums);
  norm_bf16_kernel<<<16384, 256, 0, stream>>>(bufB, sums, g0, be0);

  // layer 1
  gemm_kernel<512, 0><<<dim3(64, 4, 8), 256, 0, stream>>>(wb1, bufB, bufA);
  stats_bf16_kernel<<<512, 256, 0, stream>>>(bufA, sums + 1024);
  norm_bf16_kernel<<<16384, 256, 0, stream>>>(bufA, sums + 1024, g1, be1);

  // layer 2 (f32 epilogue straight into d_out, [b][o][n])
  gemm_kernel<256, 1><<<dim3(64, 2, 8), 256, 0, stream>>>(wb2, bufA, (void*)d_out);
  stats_f32_kernel<<<dim3(256, 8), 256, 0, stream>>>((const float*)d_out, sums + 2048);
  norm_out_kernel<<<dim3(8, 256, 8), 256, 0, stream>>>((float*)d_out, sums + 2048, g2, be2);
}